// Round 8
// baseline (318.897 us; speedup 1.0000x reference)
//
#include <hip/hip_runtime.h>
#include <hip/hip_bf16.h>
#include <stdint.h>

#define N_VOX 131072
#define KVOL  27
#define PPK   65536
#define CIN   64
#define COUT  64
#define TOT   (KVOL * PPK)   // 1769472 pairs

typedef __attribute__((ext_vector_type(8))) short short8;
typedef __attribute__((ext_vector_type(4))) float f32x4;

__device__ __forceinline__ void gl_lds16(const void* g, void* l) {
  __builtin_amdgcn_global_load_lds(
      (const __attribute__((address_space(1))) unsigned int*)g,
      (__attribute__((address_space(3))) unsigned int*)l,
      16, 0, 0);
}

__device__ __forceinline__ unsigned short f2bf(float f) {
  __hip_bfloat16 h = __float2bfloat16(f);
  return *reinterpret_cast<unsigned short*>(&h);
}

// ---------------- fused prep: cast, transpose, NON-RETURNING hist ----------------
// blocks [0,4096): cast in_feats fp32->bf16 (8 elem/thread)
// blocks [4096,4123): kernel [27][CIN][COUT] -> Wt [27][COUT][CIN] bf16
// blocks [4123,...): atomicAdd(&cnt[omap[e]],1)  -- fire-and-forget (fast path per R1)

__global__ __launch_bounds__(256) void prep_kernel(
    const float* __restrict__ in, unsigned short* __restrict__ inb,
    const float* __restrict__ w, unsigned short* __restrict__ wt,
    const int* __restrict__ omap, int* __restrict__ cnt,
    int do_hist) {
  int b = blockIdx.x;
  if (b < 4096) {
    int i = b * 256 + threadIdx.x;
    const float4* in4 = (const float4*)in;
    float4 f0 = in4[2 * i], f1 = in4[2 * i + 1];
    union { unsigned short u[8]; short8 v; } r;
    r.u[0] = f2bf(f0.x); r.u[1] = f2bf(f0.y); r.u[2] = f2bf(f0.z); r.u[3] = f2bf(f0.w);
    r.u[4] = f2bf(f1.x); r.u[5] = f2bf(f1.y); r.u[6] = f2bf(f1.z); r.u[7] = f2bf(f1.w);
    ((short8*)inb)[i] = r.v;
  } else if (b < 4096 + KVOL) {
    int k = b - 4096;
    const float* wk = w + k * CIN * COUT;
    unsigned short* wtk = wt + k * CIN * COUT;
    for (int idx = threadIdx.x; idx < CIN * COUT; idx += 256) {
      int c = idx >> 6, o = idx & 63;
      wtk[o * 64 + c] = f2bf(wk[idx]);
    }
  } else if (do_hist) {
    int e = (b - 4096 - KVOL) * 256 + threadIdx.x;
    atomicAdd(&cnt[omap[e]], 1);   // no return value used -> fire-and-forget
  }
}

// single-pass scan: per-block exclusive scan + atomic global base.
// row segments are disjoint & contiguous (not row-monotonic; fine for reduce).
__global__ __launch_bounds__(256) void scan_kernel(const int* __restrict__ cnt,
                                                   int* __restrict__ ofs,
                                                   int* __restrict__ gctr) {
  __shared__ int s[256];
  __shared__ int base_s;
  int i = blockIdx.x * 256 + threadIdx.x;
  int v = cnt[i];
  s[threadIdx.x] = v; __syncthreads();
  for (int off = 1; off < 256; off <<= 1) {
    int t = (threadIdx.x >= off) ? s[threadIdx.x - off] : 0;
    __syncthreads();
    s[threadIdx.x] += t;
    __syncthreads();
  }
  if (threadIdx.x == 255) base_s = atomicAdd(gctr, s[255]);
  __syncthreads();
  ofs[i] = base_s + s[threadIdx.x] - v;
}

// ---------------- stage 1: rank (returning atomic, hidden) + gather -> MFMA -> nt-store ----------------

__global__ __launch_bounds__(256) void spconv_store_kernel(
    const unsigned short* __restrict__ inb,   // [N][64] bf16
    const unsigned short* __restrict__ wt,    // [27][COUT][CIN] bf16
    const int* __restrict__ imap,
    const int* __restrict__ omap,
    const int* __restrict__ ofs,
    int* __restrict__ cur,
    unsigned short* __restrict__ contrib) {   // [TOT][64] bf16, sorted by output row
  __shared__ __align__(16) char smem[24576];
  short* A_lds = (short*)smem;            // 16 KB: 128 pairs x 64 cin (fragment-major)
  short* B_lds = (short*)(smem + 16384);  //  8 KB: 64 cout x 64 cin
  short* C_sh  = (short*)smem;            // epilogue: [128][72] bf16
  __shared__ int perm_s[128];

  int bid = blockIdx.x;
  int k = bid >> 9;
  int pbase = (bid & 511) * 128;
  int tid = threadIdx.x;
  int wave = tid >> 6, lane = tid & 63;
  int m = lane & 15, q = lane >> 4;

  const int* imk = imap + k * PPK;
  const unsigned short* wtk = wt + k * 4096;

  // sorted slot = ofs[row] + rank; the atomic return drains at the same
  // barrier as the staging loads (overlaps GEMM latency).
  if (tid < 128) {
    int row = omap[k * PPK + pbase + tid];
    perm_s[tid] = ofs[row] + atomicAdd(&cur[row], 1);
  }

#pragma unroll
  for (int i = 0; i < 2; i++) {
    int id = wave * 2 + i;
    int t = id >> 1, s = id & 1;
    const unsigned short* g = wtk + (t * 16 + m) * 64 + s * 32 + q * 8;
    gl_lds16(g, &B_lds[(t * 128 + s * 64) * 8]);
  }
#pragma unroll
  for (int j = 0; j < 2; j++) {
    int r = wave * 2 + j;
    int row = imk[pbase + r * 16 + m];
    const unsigned short* g0 = inb + row * 64 + q * 8;
    gl_lds16(g0,      &A_lds[(r * 128)      * 8]);
    gl_lds16(g0 + 32, &A_lds[(r * 128 + 64) * 8]);
  }
  __syncthreads();

  const short8* Af = (const short8*)A_lds;
  const short8* Bf = (const short8*)B_lds;

  short8 a[2][2], b[4][2];
#pragma unroll
  for (int r2 = 0; r2 < 2; r2++) {
    int r = wave * 2 + r2;
#pragma unroll
    for (int s = 0; s < 2; s++) a[r2][s] = Af[r * 128 + s * 64 + lane];
  }
#pragma unroll
  for (int t = 0; t < 4; t++)
#pragma unroll
    for (int s = 0; s < 2; s++) b[t][s] = Bf[t * 128 + s * 64 + lane];

  __syncthreads();   // frag reads done before LDS reuse for C

  f32x4 acc[2][4];
#pragma unroll
  for (int r2 = 0; r2 < 2; r2++)
#pragma unroll
    for (int t = 0; t < 4; t++) {
      f32x4 c = {0.f, 0.f, 0.f, 0.f};
      c = __builtin_amdgcn_mfma_f32_16x16x32_bf16(a[r2][0], b[t][0], c, 0, 0, 0);
      c = __builtin_amdgcn_mfma_f32_16x16x32_bf16(a[r2][1], b[t][1], c, 0, 0, 0);
      acc[r2][t] = c;
    }

  // C layout: row(pair) = q*4 + reg, col(cout) = t*16 + m
#pragma unroll
  for (int r2 = 0; r2 < 2; r2++) {
    int pl = (wave * 2 + r2) * 16 + q * 4;
#pragma unroll
    for (int t = 0; t < 4; t++)
#pragma unroll
      for (int reg = 0; reg < 4; reg++)
        C_sh[(pl + reg) * 72 + t * 16 + m] = (short)f2bf(acc[r2][t][reg]);
  }
  __syncthreads();

  // nontemporal full-line stores to sorted slots
#pragma unroll
  for (int i = 0; i < 4; i++) {
    int id = i * 256 + tid;
    int row = id >> 3, ch = (id & 7) * 8;
    short8 v = *(const short8*)&C_sh[row * 72 + ch];
    __builtin_nontemporal_store(v, (short8*)&contrib[(size_t)perm_s[row] * 64 + ch]);
  }
}

// ---------------- stage 2: contiguous segmented reduce + bias ----------------

__global__ __launch_bounds__(256) void reduce_kernel(
    const unsigned short* __restrict__ contrib,
    const int* __restrict__ ofs,
    const int* __restrict__ cnt,
    const float* __restrict__ bias,
    float* __restrict__ out) {
  int row = blockIdx.x * 4 + (threadIdx.x >> 6);
  int lane = threadIdx.x & 63;
  int rg = lane >> 3, ch = (lane & 7) * 8;
  int s = ofs[row], n = cnt[row];

  float acc[8];
#pragma unroll
  for (int i = 0; i < 8; i++) acc[i] = 0.f;

  int j = rg;
  for (; j + 8 < n; j += 16) {
    short8 v0 = __builtin_nontemporal_load((const short8*)&contrib[(size_t)(s + j) * 64 + ch]);
    short8 v1 = __builtin_nontemporal_load((const short8*)&contrib[(size_t)(s + j + 8) * 64 + ch]);
#pragma unroll
    for (int i = 0; i < 8; i++)
      acc[i] += __uint_as_float((unsigned int)(unsigned short)v0[i] << 16);
#pragma unroll
    for (int i = 0; i < 8; i++)
      acc[i] += __uint_as_float((unsigned int)(unsigned short)v1[i] << 16);
  }
  if (j < n) {
    short8 v0 = __builtin_nontemporal_load((const short8*)&contrib[(size_t)(s + j) * 64 + ch]);
#pragma unroll
    for (int i = 0; i < 8; i++)
      acc[i] += __uint_as_float((unsigned int)(unsigned short)v0[i] << 16);
  }

#pragma unroll
  for (int mask = 8; mask < 64; mask <<= 1)
#pragma unroll
    for (int i = 0; i < 8; i++) acc[i] += __shfl_xor(acc[i], mask, 64);

  if (rg == 0) {
    float4 b0 = *(const float4*)(bias + ch);
    float4 b1 = *(const float4*)(bias + ch + 4);
    float4 r0 = {acc[0] + b0.x, acc[1] + b0.y, acc[2] + b0.z, acc[3] + b0.w};
    float4 r1 = {acc[4] + b1.x, acc[5] + b1.y, acc[6] + b1.z, acc[7] + b1.w};
    *(float4*)(out + (size_t)row * 64 + ch) = r0;
    *(float4*)(out + (size_t)row * 64 + ch + 4) = r1;
  }
}

// ---------------- fallback (atomic path) ----------------

__global__ __launch_bounds__(256) void init_out_kernel(float* __restrict__ out,
                                                       const float* __restrict__ bias) {
  int i = blockIdx.x * blockDim.x + threadIdx.x;
  float4 b = *(const float4*)(bias + ((i * 4) & 63));
  ((float4*)out)[i] = b;
}

__global__ __launch_bounds__(256) void spconv_atomic_kernel(
    const unsigned short* __restrict__ inb,
    const unsigned short* __restrict__ wt,
    const int* __restrict__ imap, const int* __restrict__ omap,
    float* __restrict__ out) {
  __shared__ __align__(16) short A_lds[128 * 64];
  __shared__ __align__(16) short B_lds[64 * 64];

  int bid = blockIdx.x;
  int k = bid >> 9;
  int pbase = (bid & 511) * 128;
  int tid = threadIdx.x;
  int wave = tid >> 6, lane = tid & 63;
  int m = lane & 15, q = lane >> 4;

  const int* imk = imap + k * PPK;
  const int* omk = omap + k * PPK;
  const unsigned short* wtk = wt + k * 4096;

#pragma unroll
  for (int i = 0; i < 2; i++) {
    int id = wave * 2 + i;
    int t = id >> 1, s = id & 1;
    const unsigned short* g = wtk + (t * 16 + m) * 64 + s * 32 + q * 8;
    gl_lds16(g, &B_lds[(t * 128 + s * 64) * 8]);
  }
#pragma unroll
  for (int j = 0; j < 2; j++) {
    int r = wave * 2 + j;
    int row = imk[pbase + r * 16 + m];
    const unsigned short* g0 = inb + row * 64 + q * 8;
    gl_lds16(g0,      &A_lds[(r * 128)      * 8]);
    gl_lds16(g0 + 32, &A_lds[(r * 128 + 64) * 8]);
  }
  __syncthreads();

  const short8* Af = (const short8*)A_lds;
  const short8* Bf = (const short8*)B_lds;
  short8 a[2][2], b[4][2];
#pragma unroll
  for (int r2 = 0; r2 < 2; r2++) {
    int r = wave * 2 + r2;
#pragma unroll
    for (int s = 0; s < 2; s++) a[r2][s] = Af[r * 128 + s * 64 + lane];
  }
#pragma unroll
  for (int t = 0; t < 4; t++)
#pragma unroll
    for (int s = 0; s < 2; s++) b[t][s] = Bf[t * 128 + s * 64 + lane];

  f32x4 acc[2][4];
#pragma unroll
  for (int r2 = 0; r2 < 2; r2++)
#pragma unroll
    for (int t = 0; t < 4; t++) {
      f32x4 c = {0.f, 0.f, 0.f, 0.f};
      c = __builtin_amdgcn_mfma_f32_16x16x32_bf16(a[r2][0], b[t][0], c, 0, 0, 0);
      c = __builtin_amdgcn_mfma_f32_16x16x32_bf16(a[r2][1], b[t][1], c, 0, 0, 0);
      acc[r2][t] = c;
    }

  int orow[2][4];
#pragma unroll
  for (int r2 = 0; r2 < 2; r2++) {
    int pr = pbase + (wave * 2 + r2) * 16 + q * 4;
#pragma unroll
    for (int reg = 0; reg < 4; reg++) orow[r2][reg] = omk[pr + reg];
  }
#pragma unroll
  for (int r2 = 0; r2 < 2; r2++)
#pragma unroll
    for (int t = 0; t < 4; t++)
#pragma unroll
      for (int reg = 0; reg < 4; reg++)
        atomicAdd(out + (size_t)orow[r2][reg] * 64 + t * 16 + m, acc[r2][t][reg]);
}

// ---------------- launch ----------------

extern "C" void kernel_launch(void* const* d_in, const int* in_sizes, int n_in,
                              void* d_out, int out_size, void* d_ws, size_t ws_size,
                              hipStream_t stream) {
  const float* in_feats = (const float*)d_in[0];
  const float* kern     = (const float*)d_in[1];
  const float* bias     = (const float*)d_in[2];
  const int*   imap     = (const int*)d_in[3];
  const int*   omap     = (const int*)d_in[4];
  float* out = (float*)d_out;

  char* ws = (char*)d_ws;
  size_t off = 0;
  auto alloc = [&](size_t bytes) { size_t o = off; off = (off + bytes + 255) & ~(size_t)255; return o; };

  size_t o_inb  = alloc((size_t)N_VOX * CIN * 2);        // 16.78 MB
  size_t o_wt   = alloc((size_t)KVOL * CIN * COUT * 2);  // 0.22 MB
  size_t o_cnt  = alloc((size_t)N_VOX * 4);              // 0.52 MB (zeroed)
  size_t o_cur  = alloc((size_t)N_VOX * 4);              // 0.52 MB (zeroed)
  size_t o_gctr = alloc(4);                              // (zeroed)
  size_t o_ofs  = alloc((size_t)N_VOX * 4);
  size_t o_ctb  = alloc((size_t)TOT * 64 * 2);           // 226.5 MB
  size_t needed = off;

  unsigned short* inb = (unsigned short*)(ws + o_inb);
  unsigned short* wt  = (unsigned short*)(ws + o_wt);
  int* cnt  = (int*)(ws + o_cnt);
  int* cur  = (int*)(ws + o_cur);
  int* gctr = (int*)(ws + o_gctr);
  int* ofs  = (int*)(ws + o_ofs);
  unsigned short* ctb = (unsigned short*)(ws + o_ctb);

  bool fast = (ws_size >= needed);

  if (fast) {
    // one memset covers cnt + cur + gctr (contiguous region)
    (void)hipMemsetAsync(cnt, 0, o_ofs - o_cnt, stream);
    prep_kernel<<<4096 + KVOL + TOT / 256, 256, 0, stream>>>(
        in_feats, inb, kern, wt, omap, cnt, 1);
    scan_kernel<<<N_VOX / 256, 256, 0, stream>>>(cnt, ofs, gctr);
    spconv_store_kernel<<<KVOL * (PPK / 128), 256, 0, stream>>>(
        inb, wt, imap, omap, ofs, cur, ctb);
    reduce_kernel<<<N_VOX / 4, 256, 0, stream>>>(ctb, ofs, cnt, bias, out);
  } else {
    prep_kernel<<<4096 + KVOL, 256, 0, stream>>>(
        in_feats, inb, kern, wt, omap, nullptr, 0);
    init_out_kernel<<<(N_VOX * COUT / 4) / 256, 256, 0, stream>>>(out, bias);
    spconv_atomic_kernel<<<KVOL * (PPK / 128), 256, 0, stream>>>(inb, wt, imap, omap, out);
  }
}

// Round 9
// 302.351 us; speedup vs baseline: 1.0547x; 1.0547x over previous
//
#include <hip/hip_runtime.h>
#include <hip/hip_bf16.h>
#include <stdint.h>

#define N_VOX 131072
#define KVOL  27
#define PPK   65536
#define CIN   64
#define COUT  64
#define TOT   (KVOL * PPK)   // 1769472 pairs
#define RANK_BLOCKS 864      // TOT / (256 threads * 8 per thread)

typedef __attribute__((ext_vector_type(8))) short short8;
typedef __attribute__((ext_vector_type(4))) float f32x4;

__device__ __forceinline__ void gl_lds16(const void* g, void* l) {
  __builtin_amdgcn_global_load_lds(
      (const __attribute__((address_space(1))) unsigned int*)g,
      (__attribute__((address_space(3))) unsigned int*)l,
      16, 0, 0);
}

__device__ __forceinline__ unsigned short f2bf(float f) {
  __hip_bfloat16 h = __float2bfloat16(f);
  return *reinterpret_cast<unsigned short*>(&h);
}

// ---------------- fused prep + batched rank ----------------
// blocks [0,4096): cast in_feats fp32->bf16 (8 elem/thread)
// blocks [4096,4123): kernel [27][CIN][COUT] -> Wt [27][COUT][CIN] bf16
// blocks [4123,4123+864): rank, 8 atomics per thread (deep pipeline)

__global__ __launch_bounds__(256) void prep_rank_kernel(
    const float* __restrict__ in, unsigned short* __restrict__ inb,
    const float* __restrict__ w, unsigned short* __restrict__ wt,
    const int* __restrict__ omap, int* __restrict__ cnt, int* __restrict__ rank,
    int do_rank) {
  int b = blockIdx.x;
  if (b < 4096) {
    int i = b * 256 + threadIdx.x;
    const float4* in4 = (const float4*)in;
    float4 f0 = in4[2 * i], f1 = in4[2 * i + 1];
    union { unsigned short u[8]; short8 v; } r;
    r.u[0] = f2bf(f0.x); r.u[1] = f2bf(f0.y); r.u[2] = f2bf(f0.z); r.u[3] = f2bf(f0.w);
    r.u[4] = f2bf(f1.x); r.u[5] = f2bf(f1.y); r.u[6] = f2bf(f1.z); r.u[7] = f2bf(f1.w);
    ((short8*)inb)[i] = r.v;
  } else if (b < 4096 + KVOL) {
    int k = b - 4096;
    const float* wk = w + k * CIN * COUT;
    unsigned short* wtk = wt + k * CIN * COUT;
    for (int idx = threadIdx.x; idx < CIN * COUT; idx += 256) {
      int c = idx >> 6, o = idx & 63;
      wtk[o * 64 + c] = f2bf(wk[idx]);
    }
  } else if (do_rank) {
    int e0 = ((b - 4096 - KVOL) * 256 + threadIdx.x) * 8;
    int4 o0 = *(const int4*)(omap + e0);
    int4 o1 = *(const int4*)(omap + e0 + 4);
    int r0, r1, r2, r3, r4, r5, r6, r7;
    // 8 independent returning atomics issued back-to-back; compiler emits
    // one waitcnt before the packed stores -> latency amortized 8-deep.
    r0 = atomicAdd(&cnt[o0.x], 1);
    r1 = atomicAdd(&cnt[o0.y], 1);
    r2 = atomicAdd(&cnt[o0.z], 1);
    r3 = atomicAdd(&cnt[o0.w], 1);
    r4 = atomicAdd(&cnt[o1.x], 1);
    r5 = atomicAdd(&cnt[o1.y], 1);
    r6 = atomicAdd(&cnt[o1.z], 1);
    r7 = atomicAdd(&cnt[o1.w], 1);
    *(int4*)(rank + e0)     = make_int4(r0, r1, r2, r3);
    *(int4*)(rank + e0 + 4) = make_int4(r4, r5, r6, r7);
  }
}

// single-pass scan: per-block exclusive scan + atomic global base.
// row segments are disjoint & contiguous (not row-monotonic; fine for reduce).
__global__ __launch_bounds__(256) void scan_kernel(const int* __restrict__ cnt,
                                                   int* __restrict__ ofs,
                                                   int* __restrict__ gctr) {
  __shared__ int s[256];
  __shared__ int base_s;
  int i = blockIdx.x * 256 + threadIdx.x;
  int v = cnt[i];
  s[threadIdx.x] = v; __syncthreads();
  for (int off = 1; off < 256; off <<= 1) {
    int t = (threadIdx.x >= off) ? s[threadIdx.x - off] : 0;
    __syncthreads();
    s[threadIdx.x] += t;
    __syncthreads();
  }
  if (threadIdx.x == 255) base_s = atomicAdd(gctr, s[255]);
  __syncthreads();
  ofs[i] = base_s + s[threadIdx.x] - v;
}

// ---------------- stage 1: gather -> MFMA -> nt-store rows at sorted positions ----------------

__global__ __launch_bounds__(256) void spconv_store_kernel(
    const unsigned short* __restrict__ inb,   // [N][64] bf16
    const unsigned short* __restrict__ wt,    // [27][COUT][CIN] bf16
    const int* __restrict__ imap,
    const int* __restrict__ omap,
    const int* __restrict__ rank,
    const int* __restrict__ ofs,
    unsigned short* __restrict__ contrib) {   // [TOT][64] bf16, sorted by output row
  __shared__ __align__(16) char smem[24576];
  short* A_lds = (short*)smem;            // 16 KB: 128 pairs x 64 cin (fragment-major)
  short* B_lds = (short*)(smem + 16384);  //  8 KB: 64 cout x 64 cin
  short* C_sh  = (short*)smem;            // epilogue: [128][72] bf16
  __shared__ int perm_s[128];

  int bid = blockIdx.x;
  int k = bid >> 9;
  int pbase = (bid & 511) * 128;
  int tid = threadIdx.x;
  int wave = tid >> 6, lane = tid & 63;
  int m = lane & 15, q = lane >> 4;

  const int* imk = imap + k * PPK;
  const unsigned short* wtk = wt + k * 4096;

  // sorted slot = rank[e] + ofs[omap[e]]  (no atomics here)
  if (tid < 128) {
    int e = k * PPK + pbase + tid;
    perm_s[tid] = rank[e] + ofs[omap[e]];
  }

#pragma unroll
  for (int i = 0; i < 2; i++) {
    int id = wave * 2 + i;
    int t = id >> 1, s = id & 1;
    const unsigned short* g = wtk + (t * 16 + m) * 64 + s * 32 + q * 8;
    gl_lds16(g, &B_lds[(t * 128 + s * 64) * 8]);
  }
#pragma unroll
  for (int j = 0; j < 2; j++) {
    int r = wave * 2 + j;
    int row = imk[pbase + r * 16 + m];
    const unsigned short* g0 = inb + row * 64 + q * 8;
    gl_lds16(g0,      &A_lds[(r * 128)      * 8]);
    gl_lds16(g0 + 32, &A_lds[(r * 128 + 64) * 8]);
  }
  __syncthreads();

  const short8* Af = (const short8*)A_lds;
  const short8* Bf = (const short8*)B_lds;

  short8 a[2][2], b[4][2];
#pragma unroll
  for (int r2 = 0; r2 < 2; r2++) {
    int r = wave * 2 + r2;
#pragma unroll
    for (int s = 0; s < 2; s++) a[r2][s] = Af[r * 128 + s * 64 + lane];
  }
#pragma unroll
  for (int t = 0; t < 4; t++)
#pragma unroll
    for (int s = 0; s < 2; s++) b[t][s] = Bf[t * 128 + s * 64 + lane];

  __syncthreads();   // frag reads done before LDS reuse for C

  f32x4 acc[2][4];
#pragma unroll
  for (int r2 = 0; r2 < 2; r2++)
#pragma unroll
    for (int t = 0; t < 4; t++) {
      f32x4 c = {0.f, 0.f, 0.f, 0.f};
      c = __builtin_amdgcn_mfma_f32_16x16x32_bf16(a[r2][0], b[t][0], c, 0, 0, 0);
      c = __builtin_amdgcn_mfma_f32_16x16x32_bf16(a[r2][1], b[t][1], c, 0, 0, 0);
      acc[r2][t] = c;
    }

  // C layout: row(pair) = q*4 + reg, col(cout) = t*16 + m
#pragma unroll
  for (int r2 = 0; r2 < 2; r2++) {
    int pl = (wave * 2 + r2) * 16 + q * 4;
#pragma unroll
    for (int t = 0; t < 4; t++)
#pragma unroll
      for (int reg = 0; reg < 4; reg++)
        C_sh[(pl + reg) * 72 + t * 16 + m] = (short)f2bf(acc[r2][t][reg]);
  }
  __syncthreads();

  // nontemporal full-line stores to sorted slots
#pragma unroll
  for (int i = 0; i < 4; i++) {
    int id = i * 256 + tid;
    int row = id >> 3, ch = (id & 7) * 8;
    short8 v = *(const short8*)&C_sh[row * 72 + ch];
    __builtin_nontemporal_store(v, (short8*)&contrib[(size_t)perm_s[row] * 64 + ch]);
  }
}

// ---------------- stage 2: contiguous segmented reduce + bias ----------------

__global__ __launch_bounds__(256) void reduce_kernel(
    const unsigned short* __restrict__ contrib,
    const int* __restrict__ ofs,
    const int* __restrict__ cnt,
    const float* __restrict__ bias,
    float* __restrict__ out) {
  int row = blockIdx.x * 4 + (threadIdx.x >> 6);
  int lane = threadIdx.x & 63;
  int rg = lane >> 3, ch = (lane & 7) * 8;
  int s = ofs[row], n = cnt[row];

  float acc[8];
#pragma unroll
  for (int i = 0; i < 8; i++) acc[i] = 0.f;

  int j = rg;
  for (; j + 8 < n; j += 16) {
    short8 v0 = __builtin_nontemporal_load((const short8*)&contrib[(size_t)(s + j) * 64 + ch]);
    short8 v1 = __builtin_nontemporal_load((const short8*)&contrib[(size_t)(s + j + 8) * 64 + ch]);
#pragma unroll
    for (int i = 0; i < 8; i++)
      acc[i] += __uint_as_float((unsigned int)(unsigned short)v0[i] << 16);
#pragma unroll
    for (int i = 0; i < 8; i++)
      acc[i] += __uint_as_float((unsigned int)(unsigned short)v1[i] << 16);
  }
  if (j < n) {
    short8 v0 = __builtin_nontemporal_load((const short8*)&contrib[(size_t)(s + j) * 64 + ch]);
#pragma unroll
    for (int i = 0; i < 8; i++)
      acc[i] += __uint_as_float((unsigned int)(unsigned short)v0[i] << 16);
  }

#pragma unroll
  for (int mask = 8; mask < 64; mask <<= 1)
#pragma unroll
    for (int i = 0; i < 8; i++) acc[i] += __shfl_xor(acc[i], mask, 64);

  if (rg == 0) {
    float4 b0 = *(const float4*)(bias + ch);
    float4 b1 = *(const float4*)(bias + ch + 4);
    float4 r0 = {acc[0] + b0.x, acc[1] + b0.y, acc[2] + b0.z, acc[3] + b0.w};
    float4 r1 = {acc[4] + b1.x, acc[5] + b1.y, acc[6] + b1.z, acc[7] + b1.w};
    *(float4*)(out + (size_t)row * 64 + ch) = r0;
    *(float4*)(out + (size_t)row * 64 + ch + 4) = r1;
  }
}

// ---------------- fallback (atomic path) ----------------

__global__ __launch_bounds__(256) void init_out_kernel(float* __restrict__ out,
                                                       const float* __restrict__ bias) {
  int i = blockIdx.x * blockDim.x + threadIdx.x;
  float4 b = *(const float4*)(bias + ((i * 4) & 63));
  ((float4*)out)[i] = b;
}

__global__ __launch_bounds__(256) void spconv_atomic_kernel(
    const unsigned short* __restrict__ inb,
    const unsigned short* __restrict__ wt,
    const int* __restrict__ imap, const int* __restrict__ omap,
    float* __restrict__ out) {
  __shared__ __align__(16) short A_lds[128 * 64];
  __shared__ __align__(16) short B_lds[64 * 64];

  int bid = blockIdx.x;
  int k = bid >> 9;
  int pbase = (bid & 511) * 128;
  int tid = threadIdx.x;
  int wave = tid >> 6, lane = tid & 63;
  int m = lane & 15, q = lane >> 4;

  const int* imk = imap + k * PPK;
  const int* omk = omap + k * PPK;
  const unsigned short* wtk = wt + k * 4096;

#pragma unroll
  for (int i = 0; i < 2; i++) {
    int id = wave * 2 + i;
    int t = id >> 1, s = id & 1;
    const unsigned short* g = wtk + (t * 16 + m) * 64 + s * 32 + q * 8;
    gl_lds16(g, &B_lds[(t * 128 + s * 64) * 8]);
  }
#pragma unroll
  for (int j = 0; j < 2; j++) {
    int r = wave * 2 + j;
    int row = imk[pbase + r * 16 + m];
    const unsigned short* g0 = inb + row * 64 + q * 8;
    gl_lds16(g0,      &A_lds[(r * 128)      * 8]);
    gl_lds16(g0 + 32, &A_lds[(r * 128 + 64) * 8]);
  }
  __syncthreads();

  const short8* Af = (const short8*)A_lds;
  const short8* Bf = (const short8*)B_lds;
  short8 a[2][2], b[4][2];
#pragma unroll
  for (int r2 = 0; r2 < 2; r2++) {
    int r = wave * 2 + r2;
#pragma unroll
    for (int s = 0; s < 2; s++) a[r2][s] = Af[r * 128 + s * 64 + lane];
  }
#pragma unroll
  for (int t = 0; t < 4; t++)
#pragma unroll
    for (int s = 0; s < 2; s++) b[t][s] = Bf[t * 128 + s * 64 + lane];

  f32x4 acc[2][4];
#pragma unroll
  for (int r2 = 0; r2 < 2; r2++)
#pragma unroll
    for (int t = 0; t < 4; t++) {
      f32x4 c = {0.f, 0.f, 0.f, 0.f};
      c = __builtin_amdgcn_mfma_f32_16x16x32_bf16(a[r2][0], b[t][0], c, 0, 0, 0);
      c = __builtin_amdgcn_mfma_f32_16x16x32_bf16(a[r2][1], b[t][1], c, 0, 0, 0);
      acc[r2][t] = c;
    }

  int orow[2][4];
#pragma unroll
  for (int r2 = 0; r2 < 2; r2++) {
    int pr = pbase + (wave * 2 + r2) * 16 + q * 4;
#pragma unroll
    for (int reg = 0; reg < 4; reg++) orow[r2][reg] = omk[pr + reg];
  }
#pragma unroll
  for (int r2 = 0; r2 < 2; r2++)
#pragma unroll
    for (int t = 0; t < 4; t++)
#pragma unroll
      for (int reg = 0; reg < 4; reg++)
        atomicAdd(out + (size_t)orow[r2][reg] * 64 + t * 16 + m, acc[r2][t][reg]);
}

// ---------------- launch ----------------

extern "C" void kernel_launch(void* const* d_in, const int* in_sizes, int n_in,
                              void* d_out, int out_size, void* d_ws, size_t ws_size,
                              hipStream_t stream) {
  const float* in_feats = (const float*)d_in[0];
  const float* kern     = (const float*)d_in[1];
  const float* bias     = (const float*)d_in[2];
  const int*   imap     = (const int*)d_in[3];
  const int*   omap     = (const int*)d_in[4];
  float* out = (float*)d_out;

  char* ws = (char*)d_ws;
  size_t off = 0;
  auto alloc = [&](size_t bytes) { size_t o = off; off = (off + bytes + 255) & ~(size_t)255; return o; };

  size_t o_inb  = alloc((size_t)N_VOX * CIN * 2);        // 16.78 MB
  size_t o_wt   = alloc((size_t)KVOL * CIN * COUT * 2);  // 0.22 MB
  size_t o_cnt  = alloc((size_t)(N_VOX + 1) * 4);        // cnt[0..N) + gctr at [N]
  size_t o_ofs  = alloc((size_t)N_VOX * 4);
  size_t o_rank = alloc((size_t)TOT * 4);                // 7.08 MB
  size_t o_ctb  = alloc((size_t)TOT * 64 * 2);           // 226.5 MB
  size_t needed = off;

  unsigned short* inb = (unsigned short*)(ws + o_inb);
  unsigned short* wt  = (unsigned short*)(ws + o_wt);
  int* cnt  = (int*)(ws + o_cnt);
  int* gctr = cnt + N_VOX;
  int* ofs  = (int*)(ws + o_ofs);
  int* rank = (int*)(ws + o_rank);
  unsigned short* ctb = (unsigned short*)(ws + o_ctb);

  bool fast = (ws_size >= needed);

  if (fast) {
    (void)hipMemsetAsync(cnt, 0, (size_t)(N_VOX + 1) * 4, stream);
    prep_rank_kernel<<<4096 + KVOL + RANK_BLOCKS, 256, 0, stream>>>(
        in_feats, inb, kern, wt, omap, cnt, rank, 1);
    scan_kernel<<<N_VOX / 256, 256, 0, stream>>>(cnt, ofs, gctr);
    spconv_store_kernel<<<KVOL * (PPK / 128), 256, 0, stream>>>(
        inb, wt, imap, omap, rank, ofs, ctb);
    reduce_kernel<<<N_VOX / 4, 256, 0, stream>>>(ctb, ofs, cnt, bias, out);
  } else {
    prep_rank_kernel<<<4096 + KVOL, 256, 0, stream>>>(
        in_feats, inb, kern, wt, omap, nullptr, nullptr, 0);
    init_out_kernel<<<(N_VOX * COUT / 4) / 256, 256, 0, stream>>>(out, bias);
    spconv_atomic_kernel<<<KVOL * (PPK / 128), 256, 0, stream>>>(inb, wt, imap, omap, out);
  }
}